// Round 14
// baseline (340.273 us; speedup 1.0000x reference)
//
#include <hip/hip_runtime.h>
#include <hip/hip_bf16.h>

typedef _Float16 f16;
typedef f16 v8h __attribute__((ext_vector_type(8)));
typedef float v4f __attribute__((ext_vector_type(4)));
typedef float v2f __attribute__((ext_vector_type(2)));
typedef unsigned short u16;
typedef unsigned int u32;

__device__ __forceinline__ u16 f2h(float f) {
  f16 h = (f16)f;
  return __builtin_bit_cast(unsigned short, h);
}
__device__ __forceinline__ float h2f(u16 u) {
  f16 h = __builtin_bit_cast(f16, u);
  return (float)h;
}
#define MFMA16(a, b, c) __builtin_amdgcn_mfma_f32_16x16x32_f16((a), (b), (c), 0, 0, 0)

// ---------------- weight prep: fp32 row-major -> fp16 transposed/padded ----------------
// ws layout (u16 element offsets):
//   WcT  [64][128]  @ 0        (from W_cast 100x50,  zero-pad n>=50, k>=100)
//   Wa0T [256][64]  @ 8192     (from W_a0  50x256,   zero-pad k>=50)
//   Wa1T [400][256] @ 24576    (from W_a1  256x400)
//   Wp0T [256][416] @ 126976   (from W_p0  400x256,  zero-pad k>=400)
//   Wp1T [256][256] @ 233472   (from W_p1  256x256)
//   Wp2T [16][256]  @ 299008   (from W_p2  256x8,    zero-pad n>=8)
__global__ void prep_weights(const float* __restrict__ Wc, const float* __restrict__ Wa0,
                             const float* __restrict__ Wa1, const float* __restrict__ Wp0,
                             const float* __restrict__ Wp1, const float* __restrict__ Wp2,
                             u16* __restrict__ ws) {
  int idx = blockIdx.x * 256 + threadIdx.x;
  float v;
  if (idx < 8192) {
    int n = idx >> 7, k = idx & 127;
    v = (n < 50 && k < 100) ? Wc[k * 50 + n] : 0.f;
  } else if (idx < 24576) {
    int i = idx - 8192; int n = i >> 6, k = i & 63;
    v = (k < 50) ? Wa0[k * 256 + n] : 0.f;
  } else if (idx < 126976) {
    int i = idx - 24576; int n = i >> 8, k = i & 255;
    v = Wa1[k * 400 + n];
  } else if (idx < 233472) {
    int i = idx - 126976; int n = i / 416, k = i - n * 416;
    v = (k < 400) ? Wp0[k * 256 + n] : 0.f;
  } else if (idx < 299008) {
    int i = idx - 233472; int n = i >> 8, k = i & 255;
    v = Wp1[k * 256 + n];
  } else if (idx < 303104) {
    int i = idx - 299008; int n = i >> 8, k = i & 255;
    v = (n < 8) ? Wp2[k * 8 + n] : 0.f;
  } else {
    return;
  }
  ws[idx] = f2h(v);
}

// ---------------- fused actor ----------------
// R22 = R21 (252-254us anchor + neutral setprio) + XOR bank-swizzle on the
// sH/sY/sP activation buffers. Diagnosis: 2.99e7 LDS bank-conflict cycles/
// dispatch (~19% of block cycles) come from the scalar-u16 MFMA epilogue
// stores: any 16B-aligned row stride has 8*stride = 0 mod 32 banks, so lanes
// q and q+2 (rows 8 apart) always collide -> 4-way conflict on every
// epilogue store. Fix: swizzle physical col with ((row>>3)&1)<<3 (swap one
// 16B block). Both sides verified analytically:
//   writes: q-groups split into disjoint bank quartets -> conflict-free
//   reads:  key depends only on (nl>>3) -> each 8-lane group's conflict-free
//           bank tiling is shifted by a constant -> still conflict-free;
//           16B alignment preserved.
// Folds into per-thread constants (zero in-loop VALU, zero registers):
//   reads : q8 -> qx*8,  qx  = q  ^ ((nl>>3)&1)
//   writes: nl -> nlx,   nlx = nl ^ ((q>>1)<<3)
// sY pad cols 400..415 are zeros (permutation-invariant). sXall/sG/sAtt
// untouched (R19: build-phase surgery regressed coalescing).
// Session ledger: 128 unified regs/wave cliff (64 arch + 64 acc); all loop
// restructures spill y (R12-R15,R17); register-neutral wins only.
// Tripwire: WRITE>100MB or dur>260us or absmax change => revert to R20.
//
// LDS map (148480 B static):
//   sAtt [64][56]       @ 0       (7168)
//   sG   [64][136]      @ 7168    (17408, dead after cast)
//   sXall[8][64][72]    @ 7168    (73728) -> end 80896
//   sH0  [64][264]      @ 80896   (33792)
//   sH1  [64][264]      @ 114688  (33792) -> end 148480
//   sY   [64][424]      @ 7168    (54272, after obj loop; sXall dead)
//   sP   [64][264]      @ 7168    (33792, after p0 reads sY)
__global__ __launch_bounds__(1024) void actor_kernel(
    const float* __restrict__ o, const float* __restrict__ g,
    const float* __restrict__ b_cast, const float* __restrict__ b_a0,
    const float* __restrict__ b_a1, const float* __restrict__ b_p0,
    const float* __restrict__ b_p1, const float* __restrict__ b_p2,
    const u16* __restrict__ wsb, float* __restrict__ out) {
  __shared__ __align__(16) char smem[148480];
  u16* sAtt = (u16*)smem;             // [64][56]
  u16* sG   = (u16*)(smem + 7168);    // [64][136]
  u16* sX0  = (u16*)(smem + 7168);    // [8][64][72]
  u16* sH0  = (u16*)(smem + 80896);   // [64][264]
  u16* sH1  = (u16*)(smem + 114688);  // [64][264]
  u16* sY   = (u16*)(smem + 7168);    // [64][424]
  u16* sP   = (u16*)(smem + 7168);    // [64][264]

  const u16* WcT  = wsb;             // [64][128]
  const u16* Wa0T = wsb + 8192;      // [256][64]
  const u16* Wa1T = wsb + 24576;     // [400][256]
  const u16* Wp0T = wsb + 126976;    // [256][416]
  const u16* Wp1T = wsb + 233472;    // [256][256]
  const u16* Wp2T = wsb + 299008;    // [16][256]

  const int tid  = threadIdx.x;
  const int lane = tid & 63;
  const int w    = tid >> 6;   // wave 0..15
  const int nl   = lane & 15;  // MFMA m/n index
  const int q    = lane >> 4;  // quad
  const int row0 = blockIdx.x * 64;
  // bank-swizzle constants (see header comment): zero in-loop cost
  const int qx  = q ^ ((nl >> 3) & 1);   // swizzled k-subblock for LDS reads
  const int nlx = nl ^ ((q >> 1) << 3);  // swizzled col for LDS epilogue writes

  // ---- stage g -> sG (fp16, K zero-padded 100->128); NT: g is single-use ----
  for (int idx = tid; idx < 64 * 128; idx += 1024) {
    int r = idx >> 7, c = idx & 127;
    float v = (c < 100) ? __builtin_nontemporal_load(&g[(size_t)(row0 + r) * 100 + c]) : 0.f;
    sG[r * 136 + c] = f2h(v);
  }
  __syncthreads();  // B1

  // ---- attention = sigmoid(g @ W_cast + b_cast); 16 waves, 1 tile each ----
  {
    const int rb = w >> 2, nbq = w & 3;
    const int col = nbq * 16 + nl;
    v4f acc = {};
#pragma unroll
    for (int kb = 0; kb < 4; ++kb) {
      v8h bh = *(const v8h*)(WcT + col * 128 + kb * 32 + q * 8);
      v8h a  = *(const v8h*)&sG[(rb * 16 + nl) * 136 + kb * 32 + q * 8];
      acc = MFMA16(a, bh, acc);
    }
    if (col < 50) {
      float bias = b_cast[col];
#pragma unroll
      for (int rg = 0; rg < 4; ++rg) {
        float v = acc[rg] + bias;
        v = 1.f / (1.f + __expf(-v));
        sAtt[(rb * 16 + q * 4 + rg) * 56 + col] = f2h(v);
      }
    }
  }
  __syncthreads();  // B2: sAtt visible; sG dead

  // ---- build sXall[8][64][72]: attenuated fp16 x for ALL objects ----
#pragma unroll
  for (int i = 0; i < 4; ++i) {
    int idx = tid + i * 1024;
    if (idx < 3840) {
      int r = idx / 60, c2 = idx - r * 60;
      const float* rp = o + (size_t)(row0 + r) * 260;
      v2f f1 = *(const v2f*)(rp + 10 + 2 * c2);   // cols 10..129
      v2f f2 = *(const v2f*)(rp + 140 + 2 * c2);  // cols 140..259
      int cc0 = 2 * c2, cc1 = cc0 + 1;
      int ob0 = cc0 / 15, j0 = cc0 - ob0 * 15;
      int ob1 = cc1 / 15, j1 = cc1 - ob1 * 15;
      u16* xr = sX0 + r * 72;
      xr[ob0 * 4608 + 20 + j0] = f2h(f1[0] * h2f(sAtt[r * 56 + 20 + j0]));
      xr[ob1 * 4608 + 20 + j1] = f2h(f1[1] * h2f(sAtt[r * 56 + 20 + j1]));
      xr[ob0 * 4608 + 35 + j0] = f2h(f2[0] * h2f(sAtt[r * 56 + 35 + j0]));
      xr[ob1 * 4608 + 35 + j1] = f2h(f2[1] * h2f(sAtt[r * 56 + 35 + j1]));
    }
  }
  if (tid < 640) {  // body part: 64 rows x 10 float2 (dest cols 0..19)
    int r = tid / 10, hh = tid - r * 10;
    const float* rp = o + (size_t)(row0 + r) * 260;
    int src = (hh < 5) ? (2 * hh) : (2 * hh + 120);
    v2f fb = *(const v2f*)(rp + src);
    int c0 = 2 * hh, c1 = c0 + 1;
    u16 x0 = f2h(fb[0] * h2f(sAtt[r * 56 + c0]));
    u16 x1 = f2h(fb[1] * h2f(sAtt[r * 56 + c1]));
    u16* xr = sX0 + r * 72;
#pragma unroll
    for (int ob = 0; ob < 8; ++ob) {
      xr[ob * 4608 + c0] = x0;
      xr[ob * 4608 + c1] = x1;
    }
  }
  // zero pad cols 50..63 for all objects (7 dword stores per (r,ob))
  for (int idx = tid; idx < 64 * 8 * 7; idx += 1024) {
    int t = idx; int uu = t % 7; t /= 7; int ob = t & 7; int r = t >> 3;
    *(u32*)&sX0[ob * 4608 + r * 72 + 50 + 2 * uu] = 0;
  }
  __syncthreads();  // B3: sXall ready

  // ---- persistent per-wave state for a1 (y accumulator in registers) ----
  const int  nb0  = w;              // y N-tile 0..15
  const int  nb1  = w + 16;         // y N-tile 16..24 (w < 9)
  const bool has1 = (nb1 < 25);     // wave-uniform
  v4f y0[4] = {};  // persistent across object loop
  v4f y1[4] = {};  // (only meaningful for w < 9)

  // ---- object loop: {a0 -> sHbuf[obj&1]; barrier; a1 -> y regs} ----
  for (int obj = 0; obj < 8; ++obj) {
    u16* sHd = (obj & 1) ? sH1 : sH0;
    const u16* sXo = sX0 + obj * 4608;

    // h = relu(x @ W_a0 + b_a0)  (K=64, N=256; wave owns n-tile w)
    {
      v4f acc[4] = {};
#pragma unroll
      for (int kb = 0; kb < 2; ++kb) {
        v8h b0 = *(const v8h*)(Wa0T + (w * 16 + nl) * 64 + kb * 32 + q * 8);
#pragma unroll
        for (int rb = 0; rb < 4; ++rb) {
          v8h a = *(const v8h*)&sXo[(rb * 16 + nl) * 72 + kb * 32 + q * 8];
          acc[rb] = MFMA16(a, b0, acc[rb]);
        }
      }
      float bias = b_a0[w * 16 + nl];
#pragma unroll
      for (int rb = 0; rb < 4; ++rb)
#pragma unroll
        for (int rg = 0; rg < 4; ++rg) {
          float v = acc[rb][rg] + bias;
          v = v > 0.f ? v : 0.f;
          sHd[(rb * 16 + q * 4 + rg) * 264 + w * 16 + nlx] = f2h(v);  // swz write
        }
    }
    __syncthreads();  // sH[obj&1] ready (1 barrier per object)

    // y += relu(h @ W_a1 + b_a1)  (K=256, N=400; wave owns nb0 [+ nb1];
    // dual-slot in one kb loop, A-fragments shared). setprio: T5 (neutral,
    // harmless). LDS reads use qx (swizzle-consistent with a0's writes).
    {
      v4f t0[4] = {}, t1[4] = {};
      __builtin_amdgcn_s_setprio(1);
#pragma unroll
      for (int kb = 0; kb < 8; ++kb) {
        v8h b0 = *(const v8h*)(Wa1T + (nb0 * 16 + nl) * 256 + kb * 32 + q * 8);
        v8h b1;
        if (has1) b1 = *(const v8h*)(Wa1T + (nb1 * 16 + nl) * 256 + kb * 32 + q * 8);
#pragma unroll
        for (int rb = 0; rb < 4; ++rb) {
          v8h a = *(const v8h*)&sHd[(rb * 16 + nl) * 264 + kb * 32 + qx * 8];  // swz read
          t0[rb] = MFMA16(a, b0, t0[rb]);
          if (has1) t1[rb] = MFMA16(a, b1, t1[rb]);
        }
      }
      __builtin_amdgcn_s_setprio(0);
      float bias0 = b_a1[nb0 * 16 + nl];
#pragma unroll
      for (int rb = 0; rb < 4; ++rb)
#pragma unroll
        for (int rg = 0; rg < 4; ++rg) {
          float v = t0[rb][rg] + bias0;
          y0[rb][rg] += (v > 0.f ? v : 0.f);
        }
      if (has1) {
        float bias1 = b_a1[nb1 * 16 + nl];
#pragma unroll
        for (int rb = 0; rb < 4; ++rb)
#pragma unroll
          for (int rg = 0; rg < 4; ++rg) {
            float v = t1[rb][rg] + bias1;
            y1[rb][rg] += (v > 0.f ? v : 0.f);
          }
      }
    }
    // no barrier: a0(obj+1) writes the OTHER sH buffer; sXall is read-only;
    // sH buffer reuse (obj+2) is dominated by the next iteration's barrier.
  }
  __syncthreads();  // all a1 reads done; sXall region becomes sY

  // ---- write y regs -> sY (fp16, [64][424], K padded 400->416) ----
  for (int idx = tid; idx < 64 * 16; idx += 1024) {
    int r = idx >> 4, c = idx & 15;
    sY[r * 424 + 400 + c] = 0;  // zeros: swizzle-permutation-invariant
  }
#pragma unroll
  for (int rb = 0; rb < 4; ++rb)
#pragma unroll
    for (int rg = 0; rg < 4; ++rg) {
      const int row = rb * 16 + q * 4 + rg;
      sY[row * 424 + nb0 * 16 + nlx] = f2h(y0[rb][rg]);            // swz write
      if (has1) sY[row * 424 + nb1 * 16 + nlx] = f2h(y1[rb][rg]);  // swz write
    }
  __syncthreads();  // sY visible

  // ---- p0 = relu(y @ W_p0 + b_p0)  (K=416, N=256; wave owns n-tile w) ----
  v4f p0acc[4] = {};
  __builtin_amdgcn_s_setprio(1);
#pragma unroll
  for (int kb = 0; kb < 13; ++kb) {
    v8h b0 = *(const v8h*)(Wp0T + (w * 16 + nl) * 416 + kb * 32 + q * 8);
#pragma unroll
    for (int rb = 0; rb < 4; ++rb) {
      v8h a = *(const v8h*)&sY[(rb * 16 + nl) * 424 + kb * 32 + qx * 8];  // swz read
      p0acc[rb] = MFMA16(a, b0, p0acc[rb]);
    }
  }
  __builtin_amdgcn_s_setprio(0);
  __syncthreads();  // all sY reads done; region becomes sP
  {
    float bias = b_p0[w * 16 + nl];
#pragma unroll
    for (int rb = 0; rb < 4; ++rb)
#pragma unroll
      for (int rg = 0; rg < 4; ++rg) {
        float v = p0acc[rb][rg] + bias;
        v = v > 0.f ? v : 0.f;
        sP[(rb * 16 + q * 4 + rg) * 264 + w * 16 + nlx] = f2h(v);  // swz write
      }
  }
  __syncthreads();  // sP visible

  // ---- p1 = relu(p0 @ W_p1 + b_p1)  (K=256, N=256; in-place rewrite) ----
  v4f p1acc[4] = {};
  __builtin_amdgcn_s_setprio(1);
#pragma unroll
  for (int kb = 0; kb < 8; ++kb) {
    v8h b0 = *(const v8h*)(Wp1T + (w * 16 + nl) * 256 + kb * 32 + q * 8);
#pragma unroll
    for (int rb = 0; rb < 4; ++rb) {
      v8h a = *(const v8h*)&sP[(rb * 16 + nl) * 264 + kb * 32 + qx * 8];  // swz read
      p1acc[rb] = MFMA16(a, b0, p1acc[rb]);
    }
  }
  __builtin_amdgcn_s_setprio(0);
  __syncthreads();  // all sP reads done
  {
    float bias = b_p1[w * 16 + nl];
#pragma unroll
    for (int rb = 0; rb < 4; ++rb)
#pragma unroll
      for (int rg = 0; rg < 4; ++rg) {
        float v = p1acc[rb][rg] + bias;
        v = v > 0.f ? v : 0.f;
        sP[(rb * 16 + q * 4 + rg) * 264 + w * 16 + nlx] = f2h(v);  // swz write
      }
  }
  __syncthreads();  // sP(p1) visible

  // ---- out = tanh(p1 @ W_p2 + b_p2)  (K=256, N=8; waves 0..3 own rows) ----
  if (w < 4) {
    v4f acc = {};
#pragma unroll
    for (int kb = 0; kb < 8; ++kb) {
      v8h a = *(const v8h*)&sP[(w * 16 + nl) * 264 + kb * 32 + qx * 8];  // swz read
      v8h b = *(const v8h*)(Wp2T + nl * 256 + kb * 32 + q * 8);
      acc = MFMA16(a, b, acc);
    }
    if (nl < 8) {
      float bias = b_p2[nl];
#pragma unroll
      for (int rg = 0; rg < 4; ++rg)
        __builtin_nontemporal_store(tanhf(acc[rg] + bias),
                                    &out[(size_t)(row0 + w * 16 + q * 4 + rg) * 8 + nl]);
    }
  }
}

extern "C" void kernel_launch(void* const* d_in, const int* in_sizes, int n_in,
                              void* d_out, int out_size, void* d_ws, size_t ws_size,
                              hipStream_t stream) {
  const float* o   = (const float*)d_in[0];
  const float* g   = (const float*)d_in[1];
  const float* Wc  = (const float*)d_in[2];
  const float* bc  = (const float*)d_in[3];
  const float* Wa0 = (const float*)d_in[4];
  const float* ba0 = (const float*)d_in[5];
  const float* Wa1 = (const float*)d_in[6];
  const float* ba1 = (const float*)d_in[7];
  const float* Wp0 = (const float*)d_in[8];
  const float* bp0 = (const float*)d_in[9];
  const float* Wp1 = (const float*)d_in[10];
  const float* bp1 = (const float*)d_in[11];
  const float* Wp2 = (const float*)d_in[12];
  const float* bp2 = (const float*)d_in[13];
  u16* ws = (u16*)d_ws;
  float* out = (float*)d_out;

  int rows = in_sizes[0] / 260;  // 65536

  prep_weights<<<1184, 256, 0, stream>>>(Wc, Wa0, Wa1, Wp0, Wp1, Wp2, ws);
  actor_kernel<<<rows / 64, 1024, 0, stream>>>(o, g, bc, ba0, ba1, bp0, bp1, bp2, ws, out);
}

// Round 15
// 336.735 us; speedup vs baseline: 1.0105x; 1.0105x over previous
//
#include <hip/hip_runtime.h>
#include <hip/hip_bf16.h>

typedef _Float16 f16;
typedef f16 v8h __attribute__((ext_vector_type(8)));
typedef float v4f __attribute__((ext_vector_type(4)));
typedef float v2f __attribute__((ext_vector_type(2)));
typedef unsigned short u16;
typedef unsigned int u32;

__device__ __forceinline__ u16 f2h(float f) {
  f16 h = (f16)f;
  return __builtin_bit_cast(unsigned short, h);
}
__device__ __forceinline__ float h2f(u16 u) {
  f16 h = __builtin_bit_cast(f16, u);
  return (float)h;
}
#define MFMA16(a, b, c) __builtin_amdgcn_mfma_f32_16x16x32_f16((a), (b), (c), 0, 0, 0)

// ---------------- weight prep: fp32 row-major -> fp16 transposed/padded ----------------
// ws layout (u16 element offsets):
//   WcT  [64][128]  @ 0        (from W_cast 100x50,  zero-pad n>=50, k>=100)
//   Wa0T [256][64]  @ 8192     (from W_a0  50x256,   zero-pad k>=50)
//   Wa1T [400][256] @ 24576    (from W_a1  256x400)
//   Wp0T [256][416] @ 126976   (from W_p0  400x256,  zero-pad k>=400)
//   Wp1T [256][256] @ 233472   (from W_p1  256x256)
//   Wp2T [16][256]  @ 299008   (from W_p2  256x8,    zero-pad n>=8)
__global__ void prep_weights(const float* __restrict__ Wc, const float* __restrict__ Wa0,
                             const float* __restrict__ Wa1, const float* __restrict__ Wp0,
                             const float* __restrict__ Wp1, const float* __restrict__ Wp2,
                             u16* __restrict__ ws) {
  int idx = blockIdx.x * 256 + threadIdx.x;
  float v;
  if (idx < 8192) {
    int n = idx >> 7, k = idx & 127;
    v = (n < 50 && k < 100) ? Wc[k * 50 + n] : 0.f;
  } else if (idx < 24576) {
    int i = idx - 8192; int n = i >> 6, k = i & 63;
    v = (k < 50) ? Wa0[k * 256 + n] : 0.f;
  } else if (idx < 126976) {
    int i = idx - 24576; int n = i >> 8, k = i & 255;
    v = Wa1[k * 400 + n];
  } else if (idx < 233472) {
    int i = idx - 126976; int n = i / 416, k = i - n * 416;
    v = (k < 400) ? Wp0[k * 256 + n] : 0.f;
  } else if (idx < 299008) {
    int i = idx - 233472; int n = i >> 8, k = i & 255;
    v = Wp1[k * 256 + n];
  } else if (idx < 303104) {
    int i = idx - 299008; int n = i >> 8, k = i & 255;
    v = (n < 8) ? Wp2[k * 8 + n] : 0.f;
  } else {
    return;
  }
  ws[idx] = f2h(v);
}

// ---------------- fused actor ----------------
// R23 (FINAL) == R21 == R20 structure + neutral setprio: the session's best
// measured configuration (252-254us, reproduced across 5 containers).
// R22 post-mortem: XOR bank-swizzle of sH/sY/sP left SQ_LDS_BANK_CONFLICT
// byte-identical (2.988e7) -> the conflicts are NOT inter-bank collisions of
// the epilogue stores; most plausibly same-dword u16 write pairs (lanes
// nl, nl^1 share a dword), which only per-lane packing fixes -- and packed
// epilogues are PROVEN to spill (R15). Reverted.
// Session ledger (final):
//  * 1024 thr / 16 waves / 1 block/CU; unified reg cliff 128/wave
//    (64 arch VGPR + 64 acc for y0,y1,t0,t1). VGPR_Count=64 in all rounds.
//  * Spill probes (all failed): reg o-prefetch (R12), staging placement
//    (R13), unroll1/slot-split/launch-bounds (R14), packed v2u epilogues
//    (R15), a0/a1 pipeline reorder (R17). Each -> 0.05-2.3 GB scratch.
//  * Neutral probes: setprio T5 (R21), LDS XOR swizzle (R22).
//  * Regression: per-thread strip staging broke coalescing (R19).
//  * Banked wins: 16-wave reg-y (R9: 445->285), hoisted sXall + sH dbuf
//    1-barrier/obj (R16: 285->252).
//  * Plateau analysis: MFMA floor 60us = 24% of wall; MfmaUtil 25.6% ==
//    pinned at floor fraction; HBM 4.5%; remainder is the barrier-serialized
//    LDS phase chain, undeepenable without registers the backend won't give.
//
// LDS map (148480 B static):
//   sAtt [64][56]       @ 0       (7168)
//   sG   [64][136]      @ 7168    (17408, dead after cast)
//   sXall[8][64][72]    @ 7168    (73728) -> end 80896
//   sH0  [64][264]      @ 80896   (33792)
//   sH1  [64][264]      @ 114688  (33792) -> end 148480
//   sY   [64][424]      @ 7168    (54272, after obj loop; sXall dead)
//   sP   [64][264]      @ 7168    (33792, after p0 reads sY)
__global__ __launch_bounds__(1024) void actor_kernel(
    const float* __restrict__ o, const float* __restrict__ g,
    const float* __restrict__ b_cast, const float* __restrict__ b_a0,
    const float* __restrict__ b_a1, const float* __restrict__ b_p0,
    const float* __restrict__ b_p1, const float* __restrict__ b_p2,
    const u16* __restrict__ wsb, float* __restrict__ out) {
  __shared__ __align__(16) char smem[148480];
  u16* sAtt = (u16*)smem;             // [64][56]
  u16* sG   = (u16*)(smem + 7168);    // [64][136]
  u16* sX0  = (u16*)(smem + 7168);    // [8][64][72]
  u16* sH0  = (u16*)(smem + 80896);   // [64][264]
  u16* sH1  = (u16*)(smem + 114688);  // [64][264]
  u16* sY   = (u16*)(smem + 7168);    // [64][424]
  u16* sP   = (u16*)(smem + 7168);    // [64][264]

  const u16* WcT  = wsb;             // [64][128]
  const u16* Wa0T = wsb + 8192;      // [256][64]
  const u16* Wa1T = wsb + 24576;     // [400][256]
  const u16* Wp0T = wsb + 126976;    // [256][416]
  const u16* Wp1T = wsb + 233472;    // [256][256]
  const u16* Wp2T = wsb + 299008;    // [16][256]

  const int tid  = threadIdx.x;
  const int lane = tid & 63;
  const int w    = tid >> 6;   // wave 0..15
  const int nl   = lane & 15;  // MFMA m/n index
  const int q    = lane >> 4;  // quad
  const int row0 = blockIdx.x * 64;

  // ---- stage g -> sG (fp16, K zero-padded 100->128); NT: g is single-use ----
  for (int idx = tid; idx < 64 * 128; idx += 1024) {
    int r = idx >> 7, c = idx & 127;
    float v = (c < 100) ? __builtin_nontemporal_load(&g[(size_t)(row0 + r) * 100 + c]) : 0.f;
    sG[r * 136 + c] = f2h(v);
  }
  __syncthreads();  // B1

  // ---- attention = sigmoid(g @ W_cast + b_cast); 16 waves, 1 tile each ----
  {
    const int rb = w >> 2, nbq = w & 3;
    const int col = nbq * 16 + nl;
    v4f acc = {};
#pragma unroll
    for (int kb = 0; kb < 4; ++kb) {
      v8h bh = *(const v8h*)(WcT + col * 128 + kb * 32 + q * 8);
      v8h a  = *(const v8h*)&sG[(rb * 16 + nl) * 136 + kb * 32 + q * 8];
      acc = MFMA16(a, bh, acc);
    }
    if (col < 50) {
      float bias = b_cast[col];
#pragma unroll
      for (int rg = 0; rg < 4; ++rg) {
        float v = acc[rg] + bias;
        v = 1.f / (1.f + __expf(-v));
        sAtt[(rb * 16 + q * 4 + rg) * 56 + col] = f2h(v);
      }
    }
  }
  __syncthreads();  // B2: sAtt visible; sG dead

  // ---- build sXall[8][64][72]: attenuated fp16 x for ALL objects ----
#pragma unroll
  for (int i = 0; i < 4; ++i) {
    int idx = tid + i * 1024;
    if (idx < 3840) {
      int r = idx / 60, c2 = idx - r * 60;
      const float* rp = o + (size_t)(row0 + r) * 260;
      v2f f1 = *(const v2f*)(rp + 10 + 2 * c2);   // cols 10..129
      v2f f2 = *(const v2f*)(rp + 140 + 2 * c2);  // cols 140..259
      int cc0 = 2 * c2, cc1 = cc0 + 1;
      int ob0 = cc0 / 15, j0 = cc0 - ob0 * 15;
      int ob1 = cc1 / 15, j1 = cc1 - ob1 * 15;
      u16* xr = sX0 + r * 72;
      xr[ob0 * 4608 + 20 + j0] = f2h(f1[0] * h2f(sAtt[r * 56 + 20 + j0]));
      xr[ob1 * 4608 + 20 + j1] = f2h(f1[1] * h2f(sAtt[r * 56 + 20 + j1]));
      xr[ob0 * 4608 + 35 + j0] = f2h(f2[0] * h2f(sAtt[r * 56 + 35 + j0]));
      xr[ob1 * 4608 + 35 + j1] = f2h(f2[1] * h2f(sAtt[r * 56 + 35 + j1]));
    }
  }
  if (tid < 640) {  // body part: 64 rows x 10 float2 (dest cols 0..19)
    int r = tid / 10, hh = tid - r * 10;
    const float* rp = o + (size_t)(row0 + r) * 260;
    int src = (hh < 5) ? (2 * hh) : (2 * hh + 120);
    v2f fb = *(const v2f*)(rp + src);
    int c0 = 2 * hh, c1 = c0 + 1;
    u16 x0 = f2h(fb[0] * h2f(sAtt[r * 56 + c0]));
    u16 x1 = f2h(fb[1] * h2f(sAtt[r * 56 + c1]));
    u16* xr = sX0 + r * 72;
#pragma unroll
    for (int ob = 0; ob < 8; ++ob) {
      xr[ob * 4608 + c0] = x0;
      xr[ob * 4608 + c1] = x1;
    }
  }
  // zero pad cols 50..63 for all objects (7 dword stores per (r,ob))
  for (int idx = tid; idx < 64 * 8 * 7; idx += 1024) {
    int t = idx; int uu = t % 7; t /= 7; int ob = t & 7; int r = t >> 3;
    *(u32*)&sX0[ob * 4608 + r * 72 + 50 + 2 * uu] = 0;
  }
  __syncthreads();  // B3: sXall ready

  // ---- persistent per-wave state for a1 (y accumulator in registers) ----
  const int  nb0  = w;              // y N-tile 0..15
  const int  nb1  = w + 16;         // y N-tile 16..24 (w < 9)
  const bool has1 = (nb1 < 25);     // wave-uniform
  v4f y0[4] = {};  // persistent across object loop
  v4f y1[4] = {};  // (only meaningful for w < 9)

  // ---- object loop: {a0 -> sHbuf[obj&1]; barrier; a1 -> y regs} ----
  for (int obj = 0; obj < 8; ++obj) {
    u16* sHd = (obj & 1) ? sH1 : sH0;
    const u16* sXo = sX0 + obj * 4608;

    // h = relu(x @ W_a0 + b_a0)  (K=64, N=256; wave owns n-tile w)
    {
      v4f acc[4] = {};
#pragma unroll
      for (int kb = 0; kb < 2; ++kb) {
        v8h b0 = *(const v8h*)(Wa0T + (w * 16 + nl) * 64 + kb * 32 + q * 8);
#pragma unroll
        for (int rb = 0; rb < 4; ++rb) {
          v8h a = *(const v8h*)&sXo[(rb * 16 + nl) * 72 + kb * 32 + q * 8];
          acc[rb] = MFMA16(a, b0, acc[rb]);
        }
      }
      const int col = w * 16 + nl;
      float bias = b_a0[col];
#pragma unroll
      for (int rb = 0; rb < 4; ++rb)
#pragma unroll
        for (int rg = 0; rg < 4; ++rg) {
          float v = acc[rb][rg] + bias;
          v = v > 0.f ? v : 0.f;
          sHd[(rb * 16 + q * 4 + rg) * 264 + col] = f2h(v);
        }
    }
    __syncthreads();  // sH[obj&1] ready (1 barrier per object)

    // y += relu(h @ W_a1 + b_a1)  (K=256, N=400; wave owns nb0 [+ nb1];
    // dual-slot in one kb loop, A-fragments shared). setprio: T5 (neutral,
    // harmless -- kept for scheduler headroom).
    {
      v4f t0[4] = {}, t1[4] = {};
      __builtin_amdgcn_s_setprio(1);
#pragma unroll
      for (int kb = 0; kb < 8; ++kb) {
        v8h b0 = *(const v8h*)(Wa1T + (nb0 * 16 + nl) * 256 + kb * 32 + q * 8);
        v8h b1;
        if (has1) b1 = *(const v8h*)(Wa1T + (nb1 * 16 + nl) * 256 + kb * 32 + q * 8);
#pragma unroll
        for (int rb = 0; rb < 4; ++rb) {
          v8h a = *(const v8h*)&sHd[(rb * 16 + nl) * 264 + kb * 32 + q * 8];
          t0[rb] = MFMA16(a, b0, t0[rb]);
          if (has1) t1[rb] = MFMA16(a, b1, t1[rb]);
        }
      }
      __builtin_amdgcn_s_setprio(0);
      float bias0 = b_a1[nb0 * 16 + nl];
#pragma unroll
      for (int rb = 0; rb < 4; ++rb)
#pragma unroll
        for (int rg = 0; rg < 4; ++rg) {
          float v = t0[rb][rg] + bias0;
          y0[rb][rg] += (v > 0.f ? v : 0.f);
        }
      if (has1) {
        float bias1 = b_a1[nb1 * 16 + nl];
#pragma unroll
        for (int rb = 0; rb < 4; ++rb)
#pragma unroll
          for (int rg = 0; rg < 4; ++rg) {
            float v = t1[rb][rg] + bias1;
            y1[rb][rg] += (v > 0.f ? v : 0.f);
          }
      }
    }
    // no barrier: a0(obj+1) writes the OTHER sH buffer; sXall is read-only;
    // sH buffer reuse (obj+2) is dominated by the next iteration's barrier.
  }
  __syncthreads();  // all a1 reads done; sXall region becomes sY

  // ---- write y regs -> sY (fp16, [64][424], K padded 400->416) ----
  for (int idx = tid; idx < 64 * 16; idx += 1024) {
    int r = idx >> 4, c = idx & 15;
    sY[r * 424 + 400 + c] = 0;
  }
#pragma unroll
  for (int rb = 0; rb < 4; ++rb)
#pragma unroll
    for (int rg = 0; rg < 4; ++rg) {
      const int row = rb * 16 + q * 4 + rg;
      sY[row * 424 + nb0 * 16 + nl] = f2h(y0[rb][rg]);
      if (has1) sY[row * 424 + nb1 * 16 + nl] = f2h(y1[rb][rg]);
    }
  __syncthreads();  // sY visible

  // ---- p0 = relu(y @ W_p0 + b_p0)  (K=416, N=256; wave owns n-tile w) ----
  v4f p0acc[4] = {};
  __builtin_amdgcn_s_setprio(1);
#pragma unroll
  for (int kb = 0; kb < 13; ++kb) {
    v8h b0 = *(const v8h*)(Wp0T + (w * 16 + nl) * 416 + kb * 32 + q * 8);
#pragma unroll
    for (int rb = 0; rb < 4; ++rb) {
      v8h a = *(const v8h*)&sY[(rb * 16 + nl) * 424 + kb * 32 + q * 8];
      p0acc[rb] = MFMA16(a, b0, p0acc[rb]);
    }
  }
  __builtin_amdgcn_s_setprio(0);
  __syncthreads();  // all sY reads done; region becomes sP
  {
    const int col = w * 16 + nl;
    float bias = b_p0[col];
#pragma unroll
    for (int rb = 0; rb < 4; ++rb)
#pragma unroll
      for (int rg = 0; rg < 4; ++rg) {
        float v = p0acc[rb][rg] + bias;
        v = v > 0.f ? v : 0.f;
        sP[(rb * 16 + q * 4 + rg) * 264 + col] = f2h(v);
      }
  }
  __syncthreads();  // sP visible

  // ---- p1 = relu(p0 @ W_p1 + b_p1)  (K=256, N=256; in-place rewrite) ----
  v4f p1acc[4] = {};
  __builtin_amdgcn_s_setprio(1);
#pragma unroll
  for (int kb = 0; kb < 8; ++kb) {
    v8h b0 = *(const v8h*)(Wp1T + (w * 16 + nl) * 256 + kb * 32 + q * 8);
#pragma unroll
    for (int rb = 0; rb < 4; ++rb) {
      v8h a = *(const v8h*)&sP[(rb * 16 + nl) * 264 + kb * 32 + q * 8];
      p1acc[rb] = MFMA16(a, b0, p1acc[rb]);
    }
  }
  __builtin_amdgcn_s_setprio(0);
  __syncthreads();  // all sP reads done
  {
    const int col = w * 16 + nl;
    float bias = b_p1[col];
#pragma unroll
    for (int rb = 0; rb < 4; ++rb)
#pragma unroll
      for (int rg = 0; rg < 4; ++rg) {
        float v = p1acc[rb][rg] + bias;
        v = v > 0.f ? v : 0.f;
        sP[(rb * 16 + q * 4 + rg) * 264 + col] = f2h(v);
      }
  }
  __syncthreads();  // sP(p1) visible

  // ---- out = tanh(p1 @ W_p2 + b_p2)  (K=256, N=8; waves 0..3 own rows) ----
  if (w < 4) {
    v4f acc = {};
#pragma unroll
    for (int kb = 0; kb < 8; ++kb) {
      v8h a = *(const v8h*)&sP[(w * 16 + nl) * 264 + kb * 32 + q * 8];
      v8h b = *(const v8h*)(Wp2T + nl * 256 + kb * 32 + q * 8);
      acc = MFMA16(a, b, acc);
    }
    if (nl < 8) {
      float bias = b_p2[nl];
#pragma unroll
      for (int rg = 0; rg < 4; ++rg)
        __builtin_nontemporal_store(tanhf(acc[rg] + bias),
                                    &out[(size_t)(row0 + w * 16 + q * 4 + rg) * 8 + nl]);
    }
  }
}

extern "C" void kernel_launch(void* const* d_in, const int* in_sizes, int n_in,
                              void* d_out, int out_size, void* d_ws, size_t ws_size,
                              hipStream_t stream) {
  const float* o   = (const float*)d_in[0];
  const float* g   = (const float*)d_in[1];
  const float* Wc  = (const float*)d_in[2];
  const float* bc  = (const float*)d_in[3];
  const float* Wa0 = (const float*)d_in[4];
  const float* ba0 = (const float*)d_in[5];
  const float* Wa1 = (const float*)d_in[6];
  const float* ba1 = (const float*)d_in[7];
  const float* Wp0 = (const float*)d_in[8];
  const float* bp0 = (const float*)d_in[9];
  const float* Wp1 = (const float*)d_in[10];
  const float* bp1 = (const float*)d_in[11];
  const float* Wp2 = (const float*)d_in[12];
  const float* bp2 = (const float*)d_in[13];
  u16* ws = (u16*)d_ws;
  float* out = (float*)d_out;

  int rows = in_sizes[0] / 260;  // 65536

  prep_weights<<<1184, 256, 0, stream>>>(Wc, Wa0, Wa1, Wp0, Wp1, Wp2, ws);
  actor_kernel<<<rows / 64, 1024, 0, stream>>>(o, g, bc, ba0, ba1, bp0, bp1, bp2, ws, out);
}

// Round 16
// 334.183 us; speedup vs baseline: 1.0182x; 1.0076x over previous
//
#include <hip/hip_runtime.h>
#include <hip/hip_bf16.h>

typedef _Float16 f16;
typedef f16 v8h __attribute__((ext_vector_type(8)));
typedef float v4f __attribute__((ext_vector_type(4)));
typedef float v2f __attribute__((ext_vector_type(2)));
typedef unsigned short u16;
typedef unsigned int u32;

__device__ __forceinline__ u16 f2h(float f) {
  f16 h = (f16)f;
  return __builtin_bit_cast(unsigned short, h);
}
__device__ __forceinline__ float h2f(u16 u) {
  f16 h = __builtin_bit_cast(f16, u);
  return (float)h;
}
#define MFMA16(a, b, c) __builtin_amdgcn_mfma_f32_16x16x32_f16((a), (b), (c), 0, 0, 0)

// ---------------- weight prep: fp32 row-major -> fp16 transposed/padded ----------------
// ws layout (u16 element offsets):
//   WcT  [64][128]  @ 0        (from W_cast 100x50,  zero-pad n>=50, k>=100)
//   Wa0T [256][64]  @ 8192     (from W_a0  50x256,   zero-pad k>=50)
//   Wa1T [400][256] @ 24576    (from W_a1  256x400)
//   Wp0T [256][416] @ 126976   (from W_p0  400x256,  zero-pad k>=400)
//   Wp1T [256][256] @ 233472   (from W_p1  256x256)
//   Wp2T [16][256]  @ 299008   (from W_p2  256x8,    zero-pad n>=8)
__global__ void prep_weights(const float* __restrict__ Wc, const float* __restrict__ Wa0,
                             const float* __restrict__ Wa1, const float* __restrict__ Wp0,
                             const float* __restrict__ Wp1, const float* __restrict__ Wp2,
                             u16* __restrict__ ws) {
  int idx = blockIdx.x * 256 + threadIdx.x;
  float v;
  if (idx < 8192) {
    int n = idx >> 7, k = idx & 127;
    v = (n < 50 && k < 100) ? Wc[k * 50 + n] : 0.f;
  } else if (idx < 24576) {
    int i = idx - 8192; int n = i >> 6, k = i & 63;
    v = (k < 50) ? Wa0[k * 256 + n] : 0.f;
  } else if (idx < 126976) {
    int i = idx - 24576; int n = i >> 8, k = i & 255;
    v = Wa1[k * 400 + n];
  } else if (idx < 233472) {
    int i = idx - 126976; int n = i / 416, k = i - n * 416;
    v = (k < 400) ? Wp0[k * 256 + n] : 0.f;
  } else if (idx < 299008) {
    int i = idx - 233472; int n = i >> 8, k = i & 255;
    v = Wp1[k * 256 + n];
  } else if (idx < 303104) {
    int i = idx - 299008; int n = i >> 8, k = i & 255;
    v = (n < 8) ? Wp2[k * 8 + n] : 0.f;
  } else {
    return;
  }
  ws[idx] = f2h(v);
}

// ---------------- fused actor ----------------
// FINAL (R24 == R23 == R21 == R20/R16 structure + neutral setprio): the
// session's measured optimum, 252us, reproduced across 6 containers.
// Session ledger (547us -> 252us, 2.17x):
//  * 1024 thr / 16 waves / 1 block/CU; unified reg cliff 128/wave
//    (64 arch VGPR + 64 acc for y0,y1,t0,t1). VGPR_Count=64 all rounds;
//    occupancy 4 waves/SIMD = 512/128, the register-pinned maximum.
//  * Spill probes (all failed, 0.05-2.3 GB scratch each): reg o-prefetch
//    (R12), staging placement (R13), unroll1/slot-split/launch-bounds (R14),
//    packed v2u epilogues (R15), a0/a1 pipeline reorder (R17).
//  * Neutral: setprio T5 (R21, kept), LDS XOR swizzle (R22 -- conflicts are
//    same-dword u16 pairs; only packing fixes them and packing spills).
//  * Regression: per-thread strip staging broke coalescing (R19).
//  * Banked wins: 16-wave reg-y (R9: 445->285), hoisted sXall + sH dbuf
//    1-barrier/obj (R16: 285->252).
//  * Plateau: MFMA floor 60us = 24% of wall; MfmaUtil 25.6% == pinned at
//    floor fraction; HBM 4.5%; remainder is the barrier-serialized LDS
//    phase chain, undeepenable without registers the backend won't grant.
//    32x32 MFMA in a1 analyzed: <=3% upside, ~60% spill risk -> not taken.
//
// LDS map (148480 B static):
//   sAtt [64][56]       @ 0       (7168)
//   sG   [64][136]      @ 7168    (17408, dead after cast)
//   sXall[8][64][72]    @ 7168    (73728) -> end 80896
//   sH0  [64][264]      @ 80896   (33792)
//   sH1  [64][264]      @ 114688  (33792) -> end 148480
//   sY   [64][424]      @ 7168    (54272, after obj loop; sXall dead)
//   sP   [64][264]      @ 7168    (33792, after p0 reads sY)
__global__ __launch_bounds__(1024) void actor_kernel(
    const float* __restrict__ o, const float* __restrict__ g,
    const float* __restrict__ b_cast, const float* __restrict__ b_a0,
    const float* __restrict__ b_a1, const float* __restrict__ b_p0,
    const float* __restrict__ b_p1, const float* __restrict__ b_p2,
    const u16* __restrict__ wsb, float* __restrict__ out) {
  __shared__ __align__(16) char smem[148480];
  u16* sAtt = (u16*)smem;             // [64][56]
  u16* sG   = (u16*)(smem + 7168);    // [64][136]
  u16* sX0  = (u16*)(smem + 7168);    // [8][64][72]
  u16* sH0  = (u16*)(smem + 80896);   // [64][264]
  u16* sH1  = (u16*)(smem + 114688);  // [64][264]
  u16* sY   = (u16*)(smem + 7168);    // [64][424]
  u16* sP   = (u16*)(smem + 7168);    // [64][264]

  const u16* WcT  = wsb;             // [64][128]
  const u16* Wa0T = wsb + 8192;      // [256][64]
  const u16* Wa1T = wsb + 24576;     // [400][256]
  const u16* Wp0T = wsb + 126976;    // [256][416]
  const u16* Wp1T = wsb + 233472;    // [256][256]
  const u16* Wp2T = wsb + 299008;    // [16][256]

  const int tid  = threadIdx.x;
  const int lane = tid & 63;
  const int w    = tid >> 6;   // wave 0..15
  const int nl   = lane & 15;  // MFMA m/n index
  const int q    = lane >> 4;  // quad
  const int row0 = blockIdx.x * 64;

  // ---- stage g -> sG (fp16, K zero-padded 100->128); NT: g is single-use ----
  for (int idx = tid; idx < 64 * 128; idx += 1024) {
    int r = idx >> 7, c = idx & 127;
    float v = (c < 100) ? __builtin_nontemporal_load(&g[(size_t)(row0 + r) * 100 + c]) : 0.f;
    sG[r * 136 + c] = f2h(v);
  }
  __syncthreads();  // B1

  // ---- attention = sigmoid(g @ W_cast + b_cast); 16 waves, 1 tile each ----
  {
    const int rb = w >> 2, nbq = w & 3;
    const int col = nbq * 16 + nl;
    v4f acc = {};
#pragma unroll
    for (int kb = 0; kb < 4; ++kb) {
      v8h bh = *(const v8h*)(WcT + col * 128 + kb * 32 + q * 8);
      v8h a  = *(const v8h*)&sG[(rb * 16 + nl) * 136 + kb * 32 + q * 8];
      acc = MFMA16(a, bh, acc);
    }
    if (col < 50) {
      float bias = b_cast[col];
#pragma unroll
      for (int rg = 0; rg < 4; ++rg) {
        float v = acc[rg] + bias;
        v = 1.f / (1.f + __expf(-v));
        sAtt[(rb * 16 + q * 4 + rg) * 56 + col] = f2h(v);
      }
    }
  }
  __syncthreads();  // B2: sAtt visible; sG dead

  // ---- build sXall[8][64][72]: attenuated fp16 x for ALL objects ----
#pragma unroll
  for (int i = 0; i < 4; ++i) {
    int idx = tid + i * 1024;
    if (idx < 3840) {
      int r = idx / 60, c2 = idx - r * 60;
      const float* rp = o + (size_t)(row0 + r) * 260;
      v2f f1 = *(const v2f*)(rp + 10 + 2 * c2);   // cols 10..129
      v2f f2 = *(const v2f*)(rp + 140 + 2 * c2);  // cols 140..259
      int cc0 = 2 * c2, cc1 = cc0 + 1;
      int ob0 = cc0 / 15, j0 = cc0 - ob0 * 15;
      int ob1 = cc1 / 15, j1 = cc1 - ob1 * 15;
      u16* xr = sX0 + r * 72;
      xr[ob0 * 4608 + 20 + j0] = f2h(f1[0] * h2f(sAtt[r * 56 + 20 + j0]));
      xr[ob1 * 4608 + 20 + j1] = f2h(f1[1] * h2f(sAtt[r * 56 + 20 + j1]));
      xr[ob0 * 4608 + 35 + j0] = f2h(f2[0] * h2f(sAtt[r * 56 + 35 + j0]));
      xr[ob1 * 4608 + 35 + j1] = f2h(f2[1] * h2f(sAtt[r * 56 + 35 + j1]));
    }
  }
  if (tid < 640) {  // body part: 64 rows x 10 float2 (dest cols 0..19)
    int r = tid / 10, hh = tid - r * 10;
    const float* rp = o + (size_t)(row0 + r) * 260;
    int src = (hh < 5) ? (2 * hh) : (2 * hh + 120);
    v2f fb = *(const v2f*)(rp + src);
    int c0 = 2 * hh, c1 = c0 + 1;
    u16 x0 = f2h(fb[0] * h2f(sAtt[r * 56 + c0]));
    u16 x1 = f2h(fb[1] * h2f(sAtt[r * 56 + c1]));
    u16* xr = sX0 + r * 72;
#pragma unroll
    for (int ob = 0; ob < 8; ++ob) {
      xr[ob * 4608 + c0] = x0;
      xr[ob * 4608 + c1] = x1;
    }
  }
  // zero pad cols 50..63 for all objects (7 dword stores per (r,ob))
  for (int idx = tid; idx < 64 * 8 * 7; idx += 1024) {
    int t = idx; int uu = t % 7; t /= 7; int ob = t & 7; int r = t >> 3;
    *(u32*)&sX0[ob * 4608 + r * 72 + 50 + 2 * uu] = 0;
  }
  __syncthreads();  // B3: sXall ready

  // ---- persistent per-wave state for a1 (y accumulator in registers) ----
  const int  nb0  = w;              // y N-tile 0..15
  const int  nb1  = w + 16;         // y N-tile 16..24 (w < 9)
  const bool has1 = (nb1 < 25);     // wave-uniform
  v4f y0[4] = {};  // persistent across object loop
  v4f y1[4] = {};  // (only meaningful for w < 9)

  // ---- object loop: {a0 -> sHbuf[obj&1]; barrier; a1 -> y regs} ----
  for (int obj = 0; obj < 8; ++obj) {
    u16* sHd = (obj & 1) ? sH1 : sH0;
    const u16* sXo = sX0 + obj * 4608;

    // h = relu(x @ W_a0 + b_a0)  (K=64, N=256; wave owns n-tile w)
    {
      v4f acc[4] = {};
#pragma unroll
      for (int kb = 0; kb < 2; ++kb) {
        v8h b0 = *(const v8h*)(Wa0T + (w * 16 + nl) * 64 + kb * 32 + q * 8);
#pragma unroll
        for (int rb = 0; rb < 4; ++rb) {
          v8h a = *(const v8h*)&sXo[(rb * 16 + nl) * 72 + kb * 32 + q * 8];
          acc[rb] = MFMA16(a, b0, acc[rb]);
        }
      }
      const int col = w * 16 + nl;
      float bias = b_a0[col];
#pragma unroll
      for (int rb = 0; rb < 4; ++rb)
#pragma unroll
        for (int rg = 0; rg < 4; ++rg) {
          float v = acc[rb][rg] + bias;
          v = v > 0.f ? v : 0.f;
          sHd[(rb * 16 + q * 4 + rg) * 264 + col] = f2h(v);
        }
    }
    __syncthreads();  // sH[obj&1] ready (1 barrier per object)

    // y += relu(h @ W_a1 + b_a1)  (K=256, N=400; wave owns nb0 [+ nb1];
    // dual-slot in one kb loop, A-fragments shared). setprio: T5 (neutral,
    // harmless -- kept for scheduler headroom).
    {
      v4f t0[4] = {}, t1[4] = {};
      __builtin_amdgcn_s_setprio(1);
#pragma unroll
      for (int kb = 0; kb < 8; ++kb) {
        v8h b0 = *(const v8h*)(Wa1T + (nb0 * 16 + nl) * 256 + kb * 32 + q * 8);
        v8h b1;
        if (has1) b1 = *(const v8h*)(Wa1T + (nb1 * 16 + nl) * 256 + kb * 32 + q * 8);
#pragma unroll
        for (int rb = 0; rb < 4; ++rb) {
          v8h a = *(const v8h*)&sHd[(rb * 16 + nl) * 264 + kb * 32 + q * 8];
          t0[rb] = MFMA16(a, b0, t0[rb]);
          if (has1) t1[rb] = MFMA16(a, b1, t1[rb]);
        }
      }
      __builtin_amdgcn_s_setprio(0);
      float bias0 = b_a1[nb0 * 16 + nl];
#pragma unroll
      for (int rb = 0; rb < 4; ++rb)
#pragma unroll
        for (int rg = 0; rg < 4; ++rg) {
          float v = t0[rb][rg] + bias0;
          y0[rb][rg] += (v > 0.f ? v : 0.f);
        }
      if (has1) {
        float bias1 = b_a1[nb1 * 16 + nl];
#pragma unroll
        for (int rb = 0; rb < 4; ++rb)
#pragma unroll
          for (int rg = 0; rg < 4; ++rg) {
            float v = t1[rb][rg] + bias1;
            y1[rb][rg] += (v > 0.f ? v : 0.f);
          }
      }
    }
    // no barrier: a0(obj+1) writes the OTHER sH buffer; sXall is read-only;
    // sH buffer reuse (obj+2) is dominated by the next iteration's barrier.
  }
  __syncthreads();  // all a1 reads done; sXall region becomes sY

  // ---- write y regs -> sY (fp16, [64][424], K padded 400->416) ----
  for (int idx = tid; idx < 64 * 16; idx += 1024) {
    int r = idx >> 4, c = idx & 15;
    sY[r * 424 + 400 + c] = 0;
  }
#pragma unroll
  for (int rb = 0; rb < 4; ++rb)
#pragma unroll
    for (int rg = 0; rg < 4; ++rg) {
      const int row = rb * 16 + q * 4 + rg;
      sY[row * 424 + nb0 * 16 + nl] = f2h(y0[rb][rg]);
      if (has1) sY[row * 424 + nb1 * 16 + nl] = f2h(y1[rb][rg]);
    }
  __syncthreads();  // sY visible

  // ---- p0 = relu(y @ W_p0 + b_p0)  (K=416, N=256; wave owns n-tile w) ----
  v4f p0acc[4] = {};
  __builtin_amdgcn_s_setprio(1);
#pragma unroll
  for (int kb = 0; kb < 13; ++kb) {
    v8h b0 = *(const v8h*)(Wp0T + (w * 16 + nl) * 416 + kb * 32 + q * 8);
#pragma unroll
    for (int rb = 0; rb < 4; ++rb) {
      v8h a = *(const v8h*)&sY[(rb * 16 + nl) * 424 + kb * 32 + q * 8];
      p0acc[rb] = MFMA16(a, b0, p0acc[rb]);
    }
  }
  __builtin_amdgcn_s_setprio(0);
  __syncthreads();  // all sY reads done; region becomes sP
  {
    const int col = w * 16 + nl;
    float bias = b_p0[col];
#pragma unroll
    for (int rb = 0; rb < 4; ++rb)
#pragma unroll
      for (int rg = 0; rg < 4; ++rg) {
        float v = p0acc[rb][rg] + bias;
        v = v > 0.f ? v : 0.f;
        sP[(rb * 16 + q * 4 + rg) * 264 + col] = f2h(v);
      }
  }
  __syncthreads();  // sP visible

  // ---- p1 = relu(p0 @ W_p1 + b_p1)  (K=256, N=256; in-place rewrite) ----
  v4f p1acc[4] = {};
  __builtin_amdgcn_s_setprio(1);
#pragma unroll
  for (int kb = 0; kb < 8; ++kb) {
    v8h b0 = *(const v8h*)(Wp1T + (w * 16 + nl) * 256 + kb * 32 + q * 8);
#pragma unroll
    for (int rb = 0; rb < 4; ++rb) {
      v8h a = *(const v8h*)&sP[(rb * 16 + nl) * 264 + kb * 32 + q * 8];
      p1acc[rb] = MFMA16(a, b0, p1acc[rb]);
    }
  }
  __builtin_amdgcn_s_setprio(0);
  __syncthreads();  // all sP reads done
  {
    const int col = w * 16 + nl;
    float bias = b_p1[col];
#pragma unroll
    for (int rb = 0; rb < 4; ++rb)
#pragma unroll
      for (int rg = 0; rg < 4; ++rg) {
        float v = p1acc[rb][rg] + bias;
        v = v > 0.f ? v : 0.f;
        sP[(rb * 16 + q * 4 + rg) * 264 + col] = f2h(v);
      }
  }
  __syncthreads();  // sP(p1) visible

  // ---- out = tanh(p1 @ W_p2 + b_p2)  (K=256, N=8; waves 0..3 own rows) ----
  if (w < 4) {
    v4f acc = {};
#pragma unroll
    for (int kb = 0; kb < 8; ++kb) {
      v8h a = *(const v8h*)&sP[(w * 16 + nl) * 264 + kb * 32 + q * 8];
      v8h b = *(const v8h*)(Wp2T + nl * 256 + kb * 32 + q * 8);
      acc = MFMA16(a, b, acc);
    }
    if (nl < 8) {
      float bias = b_p2[nl];
#pragma unroll
      for (int rg = 0; rg < 4; ++rg)
        __builtin_nontemporal_store(tanhf(acc[rg] + bias),
                                    &out[(size_t)(row0 + w * 16 + q * 4 + rg) * 8 + nl]);
    }
  }
}

extern "C" void kernel_launch(void* const* d_in, const int* in_sizes, int n_in,
                              void* d_out, int out_size, void* d_ws, size_t ws_size,
                              hipStream_t stream) {
  const float* o   = (const float*)d_in[0];
  const float* g   = (const float*)d_in[1];
  const float* Wc  = (const float*)d_in[2];
  const float* bc  = (const float*)d_in[3];
  const float* Wa0 = (const float*)d_in[4];
  const float* ba0 = (const float*)d_in[5];
  const float* Wa1 = (const float*)d_in[6];
  const float* ba1 = (const float*)d_in[7];
  const float* Wp0 = (const float*)d_in[8];
  const float* bp0 = (const float*)d_in[9];
  const float* Wp1 = (const float*)d_in[10];
  const float* bp1 = (const float*)d_in[11];
  const float* Wp2 = (const float*)d_in[12];
  const float* bp2 = (const float*)d_in[13];
  u16* ws = (u16*)d_ws;
  float* out = (float*)d_out;

  int rows = in_sizes[0] / 260;  // 65536

  prep_weights<<<1184, 256, 0, stream>>>(Wc, Wa0, Wa1, Wp0, Wp1, Wp2, ws);
  actor_kernel<<<rows / 64, 1024, 0, stream>>>(o, g, bc, ba0, ba1, bp0, bp1, bp2, ws, out);
}